// Round 3
// baseline (227.971 us; speedup 1.0000x reference)
//
#include <hip/hip_runtime.h>
#include <hip/hip_bf16.h>
#include <math.h>

typedef __attribute__((ext_vector_type(8))) short short8;
typedef __attribute__((ext_vector_type(4))) float f32x4;

constexpr int Bn = 2048, Mn = 4, Cn = 512, Dn = 256;
constexpr size_t LOGITS_OFF = 0;
constexpr size_t R_OFF   = (size_t)Bn * Cn;                 // 1,048,576
constexpr size_t SIM_OFF = R_OFF + (size_t)Bn * Mn * Cn;    // 5,242,880
constexpr size_t CTR_OFF = SIM_OFF + (size_t)Bn * Mn * Cn;  // 9,437,184
constexpr float INV_TAU = 1.0f / 0.07f;

__device__ __forceinline__ unsigned short f2bf(float f) {
  unsigned u = __float_as_uint(f);
  u += 0x7fffu + ((u >> 16) & 1u);   // round-to-nearest-even
  return (unsigned short)(u >> 16);
}

// convert 8 fp32 -> short8 bf16 (compiler fuses pairs to v_cvt_pk_bf16_f32)
__device__ __forceinline__ short8 cvt8(const float* v) {
  short8 r;
  #pragma unroll
  for (int i = 0; i < 8; i++) {
    __hip_bfloat16 h = __float2bfloat16(v[i]);
    r[i] = (short)*reinterpret_cast<unsigned short*>(&h);
  }
  return r;
}

// ---------------- K0: fp32 -> bf16 conversions (W x4, U, O) + invU ----------
struct CvtArgs {
  const float* src[6];
  unsigned short* dst[6];
  int n[6];
};

__global__ __launch_bounds__(256) void cvt_kernel(CvtArgs a,
                                                  const float* __restrict__ U,
                                                  float* __restrict__ invU) {
  int arr = blockIdx.y;
  if (arr == 6) {
    // invU[c] = 1/(||U[c]||+1e-6); one wave per concept row
    int c = blockIdx.x * 4 + (threadIdx.x >> 6);
    int lane = threadIdx.x & 63;
    float4 v = *(const float4*)&U[(size_t)c * Dn + lane * 4];
    float s = v.x*v.x + v.y*v.y + v.z*v.z + v.w*v.w;
    #pragma unroll
    for (int m = 32; m >= 1; m >>= 1) s += __shfl_xor(s, m, 64);
    if (lane == 0) invU[c] = 1.0f / (sqrtf(s) + 1e-6f);
    return;
  }
  int idx = (blockIdx.x * 256 + threadIdx.x) * 8;
  if (idx >= a.n[arr]) return;
  const float4* s = (const float4*)(a.src[arr] + idx);
  float4 v0 = s[0], v1 = s[1];
  uint4 p;
  p.x = f2bf(v0.x) | ((unsigned)f2bf(v0.y) << 16);
  p.y = f2bf(v0.z) | ((unsigned)f2bf(v0.w) << 16);
  p.z = f2bf(v1.x) | ((unsigned)f2bf(v1.y) << 16);
  p.w = f2bf(v1.z) | ((unsigned)f2bf(v1.w) << 16);
  *(uint4*)(a.dst[arr] + idx) = p;
}

// ---------------- K1: proj + LN + l2 stats, barrier-free register GEMM ------
// Block: 256 thr = 4 waves (wm = row half, wc = col half), 32 rows x 256 cols.
// Wave: 16 rows x 128 cols = 8 N-frags of 16x16x32. A/B frags loaded DIRECTLY
// from global (per-lane 16B contiguous): row/col = lane&15, k = (lane>>4)*8.
struct ProjArgs {
  const float* f[4];
  const float* b[4];
  const float* g[4];
  const float* be[4];
  const unsigned short* Wb[4];
  int K[4];
};

__global__ __launch_bounds__(256) void proj_kernel(ProjArgs a,
                                                   unsigned short* __restrict__ Zb,
                                                   float* __restrict__ invZ) {
  const int m = blockIdx.y;
  const int K = a.K[m];
  const float* __restrict__ F = a.f[m];
  const unsigned short* __restrict__ Wm = a.Wb[m];

  const int tid = threadIdx.x;
  const int w = tid >> 6, l = tid & 63;
  const int wm = w >> 1, wc = w & 1;
  const int rg = l >> 4, c16 = l & 15;
  const int row0 = blockIdx.x * 32 + wm * 16;   // global f row of frag row 0

  __shared__ float pS[2][16][2][2];
  __shared__ float qS[2][16][2][2];
  __shared__ unsigned short zS[32][264];

  f32x4 acc[8];
  #pragma unroll
  for (int i = 0; i < 8; i++) acc[i] = (f32x4){0.f, 0.f, 0.f, 0.f};

  const float* aptr = F + (size_t)(row0 + c16) * K + rg * 8;
  const unsigned short* bptr = Wm + (size_t)(wc * 128 + c16) * K + rg * 8;

  #pragma unroll 2
  for (int k0 = 0; k0 < K; k0 += 32) {
    float av[8];
    *(float4*)&av[0] = *(const float4*)(aptr + k0);
    *(float4*)&av[4] = *(const float4*)(aptr + k0 + 4);
    short8 af = cvt8(av);
    #pragma unroll
    for (int nf = 0; nf < 8; nf++) {
      short8 bv = *(const short8*)(bptr + (size_t)nf * 16 * K + k0);
      acc[nf] = __builtin_amdgcn_mfma_f32_16x16x32_bf16(af, bv, acc[nf], 0, 0, 0);
    }
  }

  // ---- epilogue: bias + LayerNorm + l2 stats (cross-wave over wc halves) ----
  float bb[8], gg[8], ee[8];
  #pragma unroll
  for (int nf = 0; nf < 8; nf++) {
    int col = wc * 128 + nf * 16 + c16;
    bb[nf] = a.b[m][col];
    gg[nf] = a.g[m][col];
    ee[nf] = a.be[m][col];
  }
  float s[4] = {0,0,0,0}, s2[4] = {0,0,0,0};
  #pragma unroll
  for (int nf = 0; nf < 8; nf++)
    #pragma unroll
    for (int j = 0; j < 4; j++) {
      float y = acc[nf][j] + bb[nf];
      acc[nf][j] = y;
      s[j] += y; s2[j] += y * y;
    }
  #pragma unroll
  for (int msk = 8; msk >= 1; msk >>= 1)
    #pragma unroll
    for (int j = 0; j < 4; j++) {
      s[j]  += __shfl_xor(s[j],  msk, 64);
      s2[j] += __shfl_xor(s2[j], msk, 64);
    }
  if (c16 == 0)
    #pragma unroll
    for (int j = 0; j < 4; j++) {
      pS[wm][rg*4+j][wc][0] = s[j];
      pS[wm][rg*4+j][wc][1] = s2[j];
    }
  __syncthreads();
  float mu[4], rs[4];
  #pragma unroll
  for (int j = 0; j < 4; j++) {
    float st  = pS[wm][rg*4+j][0][0] + pS[wm][rg*4+j][1][0];
    float s2t = pS[wm][rg*4+j][0][1] + pS[wm][rg*4+j][1][1];
    mu[j] = st * (1.0f/256.0f);
    float var = s2t * (1.0f/256.0f) - mu[j]*mu[j];
    rs[j] = rsqrtf(var + 1e-5f);
  }
  float zs[4] = {0,0,0,0};
  #pragma unroll
  for (int nf = 0; nf < 8; nf++)
    #pragma unroll
    for (int j = 0; j < 4; j++) {
      float z = (acc[nf][j] - mu[j]) * rs[j] * gg[nf] + ee[nf];
      acc[nf][j] = z;
      zs[j] += z * z;
    }
  #pragma unroll
  for (int msk = 8; msk >= 1; msk >>= 1)
    #pragma unroll
    for (int j = 0; j < 4; j++) zs[j] += __shfl_xor(zs[j], msk, 64);
  if (c16 == 0)
    #pragma unroll
    for (int j = 0; j < 4; j++) {
      qS[wm][rg*4+j][wc][0] = zs[j];
    }
  __syncthreads();
  float inv[4];
  #pragma unroll
  for (int j = 0; j < 4; j++) {
    float zt = qS[wm][rg*4+j][0][0] + qS[wm][rg*4+j][1][0];
    inv[j] = 1.0f / (sqrtf(zt) + 1e-6f);
  }
  if (c16 == 0 && wc == 0)
    #pragma unroll
    for (int j = 0; j < 4; j++)
      invZ[(size_t)(row0 + rg*4 + j) * 4 + m] = inv[j];

  // Z (bf16) -> LDS transpose -> vectorized global store
  #pragma unroll
  for (int nf = 0; nf < 8; nf++)
    #pragma unroll
    for (int j = 0; j < 4; j++)
      zS[wm*16 + rg*4 + j][wc*128 + nf*16 + c16] = f2bf(acc[nf][j]);
  __syncthreads();
  #pragma unroll
  for (int i = 0; i < 4; i++) {
    int c = tid + i * 256;               // 0..1023 chunks of 8 cols
    int row = c >> 5, colc = (c & 31) * 8;
    uint4 v = *(const uint4*)&zS[row][colc];
    *(uint4*)(Zb + ((size_t)(blockIdx.x * 32 + row) * 4 + m) * 256 + colc) = v;
  }
}

// ---------------- K2: dual GEMM + softmax/finalize, barrier-free ------------
// Wave: 16 bm-rows x 128 cols x {U,O}. Block 4 waves row-stacked = 64 rows.
// Grid (128, 4). All frags direct from global; U/O are L2-resident.
__global__ __launch_bounds__(256) void dual_kernel(
    const unsigned short* __restrict__ Zb,
    const unsigned short* __restrict__ Ub,
    const unsigned short* __restrict__ Ob,
    const float* __restrict__ invZ, const float* __restrict__ invU,
    const float* __restrict__ cls_bias, float* __restrict__ out) {
  const int tid = threadIdx.x;
  const int w = tid >> 6, l = tid & 63;
  const int rg = l >> 4, c16 = l & 15;
  const int row0 = blockIdx.x * 64 + w * 16;
  const int col0 = blockIdx.y * 128;

  f32x4 accU[8], accO[8];
  #pragma unroll
  for (int i = 0; i < 8; i++) {
    accU[i] = (f32x4){0.f, 0.f, 0.f, 0.f};
    accO[i] = (f32x4){0.f, 0.f, 0.f, 0.f};
  }

  const unsigned short* aptr = Zb + (size_t)(row0 + c16) * 256 + rg * 8;
  const unsigned short* uptr = Ub + (size_t)(col0 + c16) * 256 + rg * 8;
  const unsigned short* optr = Ob + (size_t)(col0 + c16) * 256 + rg * 8;

  #pragma unroll 2
  for (int k0 = 0; k0 < 256; k0 += 32) {
    short8 av = *(const short8*)(aptr + k0);
    #pragma unroll
    for (int nf = 0; nf < 8; nf++) {
      short8 uv = *(const short8*)(uptr + (size_t)nf * 16 * 256 + k0);
      accU[nf] = __builtin_amdgcn_mfma_f32_16x16x32_bf16(av, uv, accU[nf], 0, 0, 0);
      short8 ov = *(const short8*)(optr + (size_t)nf * 16 * 256 + k0);
      accO[nf] = __builtin_amdgcn_mfma_f32_16x16x32_bf16(av, ov, accO[nf], 0, 0, 0);
    }
  }

  // fused epilogue: sim, softmax over modalities (j == modality), r, contrib,
  // logits. acc row = rg*4 + j; rows are bm = b*4+m so j is the modality.
  const int bmb = row0 + rg * 4;
  const f32x4 iz = *(const f32x4*)&invZ[bmb];
  const int bidx = bmb >> 2;
  #pragma unroll
  for (int nf = 0; nf < 8; nf++) {
    int col = col0 + nf * 16 + c16;
    float iu = invU[col] * INV_TAU;
    f32x4 sU = accU[nf], sO = accO[nf];
    float sim0 = sU[0] * iz[0] * iu;
    float sim1 = sU[1] * iz[1] * iu;
    float sim2 = sU[2] * iz[2] * iu;
    float sim3 = sU[3] * iz[3] * iu;
    float mx = fmaxf(fmaxf(sim0, sim1), fmaxf(sim2, sim3));
    float e0 = __expf(sim0 - mx), e1 = __expf(sim1 - mx);
    float e2 = __expf(sim2 - mx), e3 = __expf(sim3 - mx);
    float rinv = 1.0f / (e0 + e1 + e2 + e3);
    float r0 = e0 * rinv, r1 = e1 * rinv, r2 = e2 * rinv, r3 = e3 * rinv;
    float ct0 = sO[0] * r0, ct1 = sO[1] * r1, ct2 = sO[2] * r2, ct3 = sO[3] * r3;
    size_t sb = (size_t)bmb * Cn + col;
    out[SIM_OFF + sb]        = sim0;
    out[SIM_OFF + sb + Cn]   = sim1;
    out[SIM_OFF + sb + 2*Cn] = sim2;
    out[SIM_OFF + sb + 3*Cn] = sim3;
    out[R_OFF + sb]          = r0;
    out[R_OFF + sb + Cn]     = r1;
    out[R_OFF + sb + 2*Cn]   = r2;
    out[R_OFF + sb + 3*Cn]   = r3;
    out[CTR_OFF + sb]        = ct0;
    out[CTR_OFF + sb + Cn]   = ct1;
    out[CTR_OFF + sb + 2*Cn] = ct2;
    out[CTR_OFF + sb + 3*Cn] = ct3;
    out[LOGITS_OFF + (size_t)bidx * Cn + col] =
        ct0 + ct1 + ct2 + ct3 + cls_bias[col];
  }
}

extern "C" void kernel_launch(void* const* d_in, const int* in_sizes, int n_in,
                              void* d_out, int out_size, void* d_ws, size_t ws_size,
                              hipStream_t stream) {
  const int fi[4] = {0, 5, 10, 15};
  const int Ks[4] = {1024, 1024, 512, 256};

  // workspace layout (bytes)
  char* ws = (char*)d_ws;
  unsigned short* Zb  = (unsigned short*)(ws + 0);           // 4,194,304 B
  unsigned short* Wb0 = (unsigned short*)(ws + 4194304);     // 524,288
  unsigned short* Wb1 = (unsigned short*)(ws + 4718592);     // 524,288
  unsigned short* Wb2 = (unsigned short*)(ws + 5242880);     // 262,144
  unsigned short* Wb3 = (unsigned short*)(ws + 5505024);     // 131,072
  unsigned short* Ub  = (unsigned short*)(ws + 5636096);     // 262,144
  unsigned short* Ob  = (unsigned short*)(ws + 5898240);     // 262,144
  float* invZ         = (float*)(ws + 6160384);              // 32,768
  float* invU         = (float*)(ws + 6193152);              // 2,048
  unsigned short* Wb[4] = {Wb0, Wb1, Wb2, Wb3};

  ProjArgs pa;
  for (int m = 0; m < 4; m++) {
    pa.f[m]  = (const float*)d_in[fi[m] + 0];
    pa.b[m]  = (const float*)d_in[fi[m] + 2];
    pa.g[m]  = (const float*)d_in[fi[m] + 3];
    pa.be[m] = (const float*)d_in[fi[m] + 4];
    pa.Wb[m] = Wb[m];
    pa.K[m]  = Ks[m];
  }
  const float* U        = (const float*)d_in[20];
  const float* O        = (const float*)d_in[21];
  const float* cls_bias = (const float*)d_in[22];

  CvtArgs ca;
  ca.src[0] = (const float*)d_in[1];   ca.dst[0] = Wb0; ca.n[0] = 262144;
  ca.src[1] = (const float*)d_in[6];   ca.dst[1] = Wb1; ca.n[1] = 262144;
  ca.src[2] = (const float*)d_in[11];  ca.dst[2] = Wb2; ca.n[2] = 131072;
  ca.src[3] = (const float*)d_in[16];  ca.dst[3] = Wb3; ca.n[3] = 65536;
  ca.src[4] = U;                       ca.dst[4] = Ub;  ca.n[4] = 131072;
  ca.src[5] = O;                       ca.dst[5] = Ob;  ca.n[5] = 131072;

  float* out = (float*)d_out;

  cvt_kernel<<<dim3(128, 7), 256, 0, stream>>>(ca, U, invU);
  proj_kernel<<<dim3(Bn / 32, 4), 256, 0, stream>>>(pa, Zb, invZ);
  dual_kernel<<<dim3((Bn * Mn) / 64, Cn / 128), 256, 0, stream>>>(
      Zb, Ub, Ob, invZ, invU, cls_bias, out);
}

// Round 4
// 192.312 us; speedup vs baseline: 1.1854x; 1.1854x over previous
//
#include <hip/hip_runtime.h>
#include <math.h>

typedef __attribute__((ext_vector_type(8))) short short8;
typedef __attribute__((ext_vector_type(4))) float f32x4;
typedef unsigned short ushort_t;

constexpr int Bn = 2048, Mn = 4, Cn = 512, Dn = 256;
constexpr size_t LOGITS_OFF = 0;
constexpr size_t R_OFF   = (size_t)Bn * Cn;                 // 1,048,576
constexpr size_t SIM_OFF = R_OFF + (size_t)Bn * Mn * Cn;    // 5,242,880
constexpr size_t CTR_OFF = SIM_OFF + (size_t)Bn * Mn * Cn;  // 9,437,184
constexpr float INV_TAU = 1.0f / 0.07f;

__device__ __forceinline__ unsigned short f2bf(float f) {
  unsigned u = __float_as_uint(f);
  u += 0x7fffu + ((u >> 16) & 1u);   // round-to-nearest-even
  return (unsigned short)(u >> 16);
}

__device__ __forceinline__ void gload16(const void* g, void* l) {
  __builtin_amdgcn_global_load_lds(
      (const __attribute__((address_space(1))) void*)g,
      (__attribute__((address_space(3))) void*)l, 16, 0, 0);
}

// ---------------- K0: fp32 -> bf16 conversions (W x4, U, O) + invU ----------
struct CvtArgs {
  const float* src[6];
  ushort_t* dst[6];
  int n[6];
};

__global__ __launch_bounds__(256) void cvt_kernel(CvtArgs a,
                                                  const float* __restrict__ U,
                                                  float* __restrict__ invU) {
  int arr = blockIdx.y;
  if (arr == 6) {
    int c = blockIdx.x * 4 + (threadIdx.x >> 6);
    int lane = threadIdx.x & 63;
    float4 v = *(const float4*)&U[(size_t)c * Dn + lane * 4];
    float s = v.x*v.x + v.y*v.y + v.z*v.z + v.w*v.w;
    #pragma unroll
    for (int m = 32; m >= 1; m >>= 1) s += __shfl_xor(s, m, 64);
    if (lane == 0) invU[c] = 1.0f / (sqrtf(s) + 1e-6f);
    return;
  }
  int idx = (blockIdx.x * 256 + threadIdx.x) * 8;
  if (idx >= a.n[arr]) return;
  const float4* s = (const float4*)(a.src[arr] + idx);
  float4 v0 = s[0], v1 = s[1];
  uint4 p;
  p.x = f2bf(v0.x) | ((unsigned)f2bf(v0.y) << 16);
  p.y = f2bf(v0.z) | ((unsigned)f2bf(v0.w) << 16);
  p.z = f2bf(v1.x) | ((unsigned)f2bf(v1.y) << 16);
  p.w = f2bf(v1.z) | ((unsigned)f2bf(v1.w) << 16);
  *(uint4*)(a.dst[arr] + idx) = p;
}

// ---------------- K1: proj + LN + l2 stats, 2-phase pipelined MFMA ----------
// Block: 256 thr = 4 waves, tile 16 rows x 256 cols (full D, LN in-block).
// Wave w owns cols w*64..w*64+64 (4 N-frags). Grid (128, 4) = 2 blocks/CU.
// LDS chunk layout [kc][row|col] (8-short chunks) -> conflict-free b128 reads.
// One __syncthreads per K-step; next tile staged BEFORE compute so the
// pre-barrier vmcnt drain overlaps the MFMA phase.
struct ProjArgs {
  const float* f[4];
  const float* b[4];
  const float* g[4];
  const float* be[4];
  const ushort_t* Wb[4];
  int K[4];
};

__global__ __launch_bounds__(256, 2) void proj_kernel(ProjArgs a,
                                                      ushort_t* __restrict__ Zb,
                                                      float* __restrict__ invZ) {
  const int m = blockIdx.y;
  const int K = a.K[m];
  const float* __restrict__ F = a.f[m];
  const ushort_t* __restrict__ Wm = a.Wb[m];

  const int tid = threadIdx.x;
  const int w = tid >> 6, l = tid & 63;
  const int rg = l >> 4, c16 = l & 15;
  const int row0 = blockIdx.x * 16;

  __shared__ ushort_t aS[2][512];     // 16 rows x 32 k  (chunks [kc][row])
  __shared__ ushort_t bS[2][8192];    // 256 cols x 32 k (chunks [kc][col])
  __shared__ float pS[4][16][2];
  __shared__ float qS[4][16];
  __shared__ ushort_t zS[16][264];

  f32x4 acc[4];
  #pragma unroll
  for (int i = 0; i < 4; i++) acc[i] = (f32x4){0.f, 0.f, 0.f, 0.f};

  const int arow = tid >> 3;          // 0..31 (valid tid<128 -> 0..15)
  const int akk  = (tid & 7) * 4;     // 0,4,..,28
  const int akc  = akk >> 3, aoff = akk & 7;

  // ---- prologue: stage tile 0 ----
  #pragma unroll
  for (int ii = 0; ii < 4; ii++) {
    int i = w + 4 * ii;               // wave-uniform
    int kc = i >> 2, colblk = i & 3;
    gload16(Wm + (size_t)(colblk * 64 + l) * K + kc * 8,
            &bS[0][(kc * 256 + colblk * 64) * 8]);
  }
  if (tid < 128) {
    float4 v = *(const float4*)(F + (size_t)(row0 + arow) * K + akk);
    uint2 p;
    p.x = f2bf(v.x) | ((unsigned)f2bf(v.y) << 16);
    p.y = f2bf(v.z) | ((unsigned)f2bf(v.w) << 16);
    *(uint2*)&aS[0][(akc * 16 + arow) * 8 + aoff] = p;
  }
  __syncthreads();

  const int NS = K >> 5;
  int cur = 0;
  float4 areg;
  for (int t = 0; t < NS; t++) {
    const int nxt = cur ^ 1;
    const bool more = (t + 1 < NS);
    const int k1 = (t + 1) << 5;
    if (more) {
      #pragma unroll
      for (int ii = 0; ii < 4; ii++) {
        int i = w + 4 * ii;
        int kc = i >> 2, colblk = i & 3;
        gload16(Wm + (size_t)(colblk * 64 + l) * K + k1 + kc * 8,
                &bS[nxt][(kc * 256 + colblk * 64) * 8]);
      }
      if (tid < 128)
        areg = *(const float4*)(F + (size_t)(row0 + arow) * K + k1 + akk);
    }
    // compute current tile
    short8 av = *(const short8*)&aS[cur][(rg * 16 + c16) * 8];
    #pragma unroll
    for (int nf = 0; nf < 4; nf++) {
      short8 bv = *(const short8*)&bS[cur][(rg * 256 + w * 64 + nf * 16 + c16) * 8];
      acc[nf] = __builtin_amdgcn_mfma_f32_16x16x32_bf16(av, bv, acc[nf], 0, 0, 0);
    }
    if (more && tid < 128) {
      uint2 p;
      p.x = f2bf(areg.x) | ((unsigned)f2bf(areg.y) << 16);
      p.y = f2bf(areg.z) | ((unsigned)f2bf(areg.w) << 16);
      *(uint2*)&aS[nxt][(akc * 16 + arow) * 8 + aoff] = p;
    }
    __syncthreads();
    cur = nxt;
  }

  // ---- epilogue: bias + LayerNorm + l2 stats ----
  float bb[4], gg[4], ee[4];
  #pragma unroll
  for (int nf = 0; nf < 4; nf++) {
    int col = w * 64 + nf * 16 + c16;
    bb[nf] = a.b[m][col];
    gg[nf] = a.g[m][col];
    ee[nf] = a.be[m][col];
  }
  float s[4] = {0,0,0,0}, s2[4] = {0,0,0,0};
  #pragma unroll
  for (int nf = 0; nf < 4; nf++)
    #pragma unroll
    for (int j = 0; j < 4; j++) {
      float y = acc[nf][j] + bb[nf];
      acc[nf][j] = y;
      s[j] += y; s2[j] += y * y;
    }
  #pragma unroll
  for (int msk = 8; msk >= 1; msk >>= 1)
    #pragma unroll
    for (int j = 0; j < 4; j++) {
      s[j]  += __shfl_xor(s[j],  msk, 64);
      s2[j] += __shfl_xor(s2[j], msk, 64);
    }
  if (c16 == 0)
    #pragma unroll
    for (int j = 0; j < 4; j++) {
      pS[w][rg*4+j][0] = s[j];
      pS[w][rg*4+j][1] = s2[j];
    }
  __syncthreads();
  float mu[4], rs[4];
  #pragma unroll
  for (int j = 0; j < 4; j++) {
    int row = rg*4 + j;
    float st  = pS[0][row][0] + pS[1][row][0] + pS[2][row][0] + pS[3][row][0];
    float s2t = pS[0][row][1] + pS[1][row][1] + pS[2][row][1] + pS[3][row][1];
    mu[j] = st * (1.0f/256.0f);
    float var = s2t * (1.0f/256.0f) - mu[j]*mu[j];
    rs[j] = rsqrtf(var + 1e-5f);
  }
  float zs[4] = {0,0,0,0};
  #pragma unroll
  for (int nf = 0; nf < 4; nf++)
    #pragma unroll
    for (int j = 0; j < 4; j++) {
      float z = (acc[nf][j] - mu[j]) * rs[j] * gg[nf] + ee[nf];
      acc[nf][j] = z;
      zs[j] += z * z;
    }
  #pragma unroll
  for (int msk = 8; msk >= 1; msk >>= 1)
    #pragma unroll
    for (int j = 0; j < 4; j++) zs[j] += __shfl_xor(zs[j], msk, 64);
  if (c16 == 0)
    #pragma unroll
    for (int j = 0; j < 4; j++) qS[w][rg*4+j] = zs[j];
  __syncthreads();
  #pragma unroll
  for (int j = 0; j < 4; j++) {
    int row = rg*4 + j;
    float zt = qS[0][row] + qS[1][row] + qS[2][row] + qS[3][row];
    float inv = 1.0f / (sqrtf(zt) + 1e-6f);
    if (c16 == 0 && w == 0)
      invZ[(size_t)(row0 + row) * 4 + m] = inv;
  }
  // Z (bf16) -> LDS transpose -> vectorized global store
  #pragma unroll
  for (int nf = 0; nf < 4; nf++)
    #pragma unroll
    for (int j = 0; j < 4; j++)
      zS[rg*4 + j][w*64 + nf*16 + c16] = f2bf(acc[nf][j]);
  __syncthreads();
  #pragma unroll
  for (int i = 0; i < 2; i++) {
    int c = tid + i * 256;               // 0..511 chunks of 8 cols
    int row = c >> 5, colc = (c & 31) * 8;
    uint4 v = *(const uint4*)&zS[row][colc];
    *(uint4*)(Zb + ((size_t)(row0 + row) * 4 + m) * 256 + colc) = v;
  }
}

// ---------------- K2: dual GEMM + softmax/finalize, 2-phase pipelined -------
// Block 256 thr = 4 waves (2x2): wave rows wr*16, cols wc2*64 x {U,O}.
// Tile 32 rows x 128 cols; grid (256, 4) = 1024 blocks = 4 blocks/CU.
__global__ __launch_bounds__(256, 4) void dual_kernel(
    const ushort_t* __restrict__ Zb,
    const ushort_t* __restrict__ Ub,
    const ushort_t* __restrict__ Ob,
    const float* __restrict__ invZ, const float* __restrict__ invU,
    const float* __restrict__ cls_bias, float* __restrict__ out) {
  const int tid = threadIdx.x;
  const int w = tid >> 6, l = tid & 63;
  const int wr = w >> 1, wc2 = w & 1;
  const int rg = l >> 4, c16 = l & 15;
  const int row0 = blockIdx.x * 32;
  const int col0 = blockIdx.y * 128;

  __shared__ ushort_t aSd[2][1024];   // 32 rows x 32 k
  __shared__ ushort_t uSd[2][4096];   // 128 cols x 32 k
  __shared__ ushort_t oSd[2][4096];

  f32x4 accU[4], accO[4];
  #pragma unroll
  for (int i = 0; i < 4; i++) {
    accU[i] = (f32x4){0.f, 0.f, 0.f, 0.f};
    accO[i] = (f32x4){0.f, 0.f, 0.f, 0.f};
  }

  // staging: 18 gload16 issues (2 A, 8 U, 8 O) spread over 4 waves
  auto stage = [&](int buf, int k0) {
    #pragma unroll
    for (int ii = 0; ii < 5; ii++) {
      int i = w + 4 * ii;      // wave-uniform
      if (i < 2) {
        // A: chunk = kc*32 + row, kc = (l>>5) + i*2, row = l&31
        gload16(Zb + (size_t)(row0 + (l & 31)) * 256 + k0 + ((l >> 5) + i * 2) * 8,
                &aSd[buf][i * 512]);
      } else if (i < 10) {
        int j = i - 2, kc = j >> 1, colblk = j & 1;
        gload16(Ub + (size_t)(col0 + colblk * 64 + l) * 256 + k0 + kc * 8,
                &uSd[buf][(kc * 128 + colblk * 64) * 8]);
      } else if (i < 18) {
        int j = i - 10, kc = j >> 1, colblk = j & 1;
        gload16(Ob + (size_t)(col0 + colblk * 64 + l) * 256 + k0 + kc * 8,
                &oSd[buf][(kc * 128 + colblk * 64) * 8]);
      }
    }
  };

  stage(0, 0);
  __syncthreads();

  int cur = 0;
  #pragma unroll
  for (int t = 0; t < 8; t++) {
    const int nxt = cur ^ 1;
    if (t + 1 < 8) stage(nxt, (t + 1) << 5);
    short8 av = *(const short8*)&aSd[cur][(rg * 32 + wr * 16 + c16) * 8];
    #pragma unroll
    for (int nf = 0; nf < 4; nf++) {
      int chunk = rg * 128 + wc2 * 64 + nf * 16 + c16;
      short8 uv = *(const short8*)&uSd[cur][chunk * 8];
      accU[nf] = __builtin_amdgcn_mfma_f32_16x16x32_bf16(av, uv, accU[nf], 0, 0, 0);
      short8 ov = *(const short8*)&oSd[cur][chunk * 8];
      accO[nf] = __builtin_amdgcn_mfma_f32_16x16x32_bf16(av, ov, accO[nf], 0, 0, 0);
    }
    __syncthreads();
    cur = nxt;
  }

  // fused epilogue: sim, softmax over modalities (j == modality), r, contrib,
  // logits. C/D frag: row = rg*4+j (bm), col = c16 (concept).
  const int bmb = row0 + wr * 16 + rg * 4;
  const f32x4 iz = *(const f32x4*)&invZ[bmb];
  const int bidx = bmb >> 2;
  #pragma unroll
  for (int nf = 0; nf < 4; nf++) {
    int col = col0 + wc2 * 64 + nf * 16 + c16;
    float iu = invU[col] * INV_TAU;
    f32x4 sU = accU[nf], sO = accO[nf];
    float sim0 = sU[0] * iz[0] * iu;
    float sim1 = sU[1] * iz[1] * iu;
    float sim2 = sU[2] * iz[2] * iu;
    float sim3 = sU[3] * iz[3] * iu;
    float mx = fmaxf(fmaxf(sim0, sim1), fmaxf(sim2, sim3));
    float e0 = __expf(sim0 - mx), e1 = __expf(sim1 - mx);
    float e2 = __expf(sim2 - mx), e3 = __expf(sim3 - mx);
    float rinv = 1.0f / (e0 + e1 + e2 + e3);
    float r0 = e0 * rinv, r1 = e1 * rinv, r2 = e2 * rinv, r3 = e3 * rinv;
    float ct0 = sO[0] * r0, ct1 = sO[1] * r1, ct2 = sO[2] * r2, ct3 = sO[3] * r3;
    size_t sb = (size_t)bmb * Cn + col;
    out[SIM_OFF + sb]        = sim0;
    out[SIM_OFF + sb + Cn]   = sim1;
    out[SIM_OFF + sb + 2*Cn] = sim2;
    out[SIM_OFF + sb + 3*Cn] = sim3;
    out[R_OFF + sb]          = r0;
    out[R_OFF + sb + Cn]     = r1;
    out[R_OFF + sb + 2*Cn]   = r2;
    out[R_OFF + sb + 3*Cn]   = r3;
    out[CTR_OFF + sb]        = ct0;
    out[CTR_OFF + sb + Cn]   = ct1;
    out[CTR_OFF + sb + 2*Cn] = ct2;
    out[CTR_OFF + sb + 3*Cn] = ct3;
    out[LOGITS_OFF + (size_t)bidx * Cn + col] =
        ct0 + ct1 + ct2 + ct3 + cls_bias[col];
  }
}

extern "C" void kernel_launch(void* const* d_in, const int* in_sizes, int n_in,
                              void* d_out, int out_size, void* d_ws, size_t ws_size,
                              hipStream_t stream) {
  const int fi[4] = {0, 5, 10, 15};
  const int Ks[4] = {1024, 1024, 512, 256};

  char* ws = (char*)d_ws;
  ushort_t* Zb  = (ushort_t*)(ws + 0);           // 4,194,304 B
  ushort_t* Wb0 = (ushort_t*)(ws + 4194304);     // 524,288
  ushort_t* Wb1 = (ushort_t*)(ws + 4718592);     // 524,288
  ushort_t* Wb2 = (ushort_t*)(ws + 5242880);     // 262,144
  ushort_t* Wb3 = (ushort_t*)(ws + 5505024);     // 131,072
  ushort_t* Ub  = (ushort_t*)(ws + 5636096);     // 262,144
  ushort_t* Ob  = (ushort_t*)(ws + 5898240);     // 262,144
  float* invZ   = (float*)(ws + 6160384);        // 32,768
  float* invU   = (float*)(ws + 6193152);        // 2,048
  ushort_t* Wb[4] = {Wb0, Wb1, Wb2, Wb3};

  ProjArgs pa;
  for (int m = 0; m < 4; m++) {
    pa.f[m]  = (const float*)d_in[fi[m] + 0];
    pa.b[m]  = (const float*)d_in[fi[m] + 2];
    pa.g[m]  = (const float*)d_in[fi[m] + 3];
    pa.be[m] = (const float*)d_in[fi[m] + 4];
    pa.Wb[m] = Wb[m];
    pa.K[m]  = Ks[m];
  }
  const float* U        = (const float*)d_in[20];
  const float* O        = (const float*)d_in[21];
  const float* cls_bias = (const float*)d_in[22];

  CvtArgs ca;
  ca.src[0] = (const float*)d_in[1];   ca.dst[0] = Wb0; ca.n[0] = 262144;
  ca.src[1] = (const float*)d_in[6];   ca.dst[1] = Wb1; ca.n[1] = 262144;
  ca.src[2] = (const float*)d_in[11];  ca.dst[2] = Wb2; ca.n[2] = 131072;
  ca.src[3] = (const float*)d_in[16];  ca.dst[3] = Wb3; ca.n[3] = 65536;
  ca.src[4] = U;                       ca.dst[4] = Ub;  ca.n[4] = 131072;
  ca.src[5] = O;                       ca.dst[5] = Ob;  ca.n[5] = 131072;

  float* out = (float*)d_out;

  cvt_kernel<<<dim3(128, 7), 256, 0, stream>>>(ca, U, invU);
  proj_kernel<<<dim3(Bn / 16, 4), 256, 0, stream>>>(pa, Zb, invZ);
  dual_kernel<<<dim3((Bn * Mn) / 32, Cn / 128), 256, 0, stream>>>(
      Zb, Ub, Ob, invZ, invU, cls_bias, out);
}

// Round 5
// 180.111 us; speedup vs baseline: 1.2657x; 1.0677x over previous
//
#include <hip/hip_runtime.h>
#include <math.h>

typedef __attribute__((ext_vector_type(8))) short short8;
typedef __attribute__((ext_vector_type(4))) float f32x4;
typedef unsigned short u16;

constexpr int Bn = 2048, Mn = 4, Cn = 512, Dn = 256;
constexpr size_t LOGITS_OFF = 0;
constexpr size_t R_OFF   = (size_t)Bn * Cn;                 // 1,048,576
constexpr size_t SIM_OFF = R_OFF + (size_t)Bn * Mn * Cn;    // 5,242,880
constexpr size_t CTR_OFF = SIM_OFF + (size_t)Bn * Mn * Cn;  // 9,437,184
constexpr float INV_TAU = 1.0f / 0.07f;

#define WAIT_STEADY asm volatile("s_waitcnt vmcnt(5) lgkmcnt(0)" ::: "memory")
#define WAIT_LAST   asm volatile("s_waitcnt vmcnt(0) lgkmcnt(0)" ::: "memory")

__device__ __forceinline__ unsigned short f2bf(float f) {
  unsigned u = __float_as_uint(f);
  u += 0x7fffu + ((u >> 16) & 1u);   // round-to-nearest-even
  return (unsigned short)(u >> 16);
}

__device__ __forceinline__ void gload16(const void* g, void* l) {
  __builtin_amdgcn_global_load_lds(
      (const __attribute__((address_space(1))) void*)g,
      (__attribute__((address_space(3))) void*)l, 16, 0, 0);
}

// ---------------- K0: fp32 -> bf16 (W x4, U, O) + invU ----------------------
// Flat chunk space: W0 32768 | W1 32768 | W2 16384 | W3 8192 | U 16384 | O 16384
// = 122880 chunks of 8 elems -> 480 blocks; blocks 480..607 do invU (4 rows ea).
struct CvtArgs {
  const float* src[6];
  u16* dst[6];
};

__global__ __launch_bounds__(256) void cvt_kernel(CvtArgs a,
                                                  const float* __restrict__ U,
                                                  float* __restrict__ invU) {
  const int blk = blockIdx.x;
  if (blk >= 480) {
    int c = (blk - 480) * 4 + (threadIdx.x >> 6);
    int lane = threadIdx.x & 63;
    float4 v = *(const float4*)&U[(size_t)c * Dn + lane * 4];
    float s = v.x*v.x + v.y*v.y + v.z*v.z + v.w*v.w;
    #pragma unroll
    for (int m = 32; m >= 1; m >>= 1) s += __shfl_xor(s, m, 64);
    if (lane == 0) invU[c] = 1.0f / (sqrtf(s) + 1e-6f);
    return;
  }
  int c = blk * 256 + threadIdx.x;
  const int ends[6] = {32768, 65536, 81920, 90112, 106496, 122880};
  int ai = 0, base = 0;
  #pragma unroll
  for (int i = 0; i < 5; i++)
    if (c >= ends[i]) { ai = i + 1; base = ends[i]; }
  int idx = (c - base) * 8;
  const float4* s = (const float4*)(a.src[ai] + idx);
  float4 v0 = s[0], v1 = s[1];
  uint4 p;
  p.x = f2bf(v0.x) | ((unsigned)f2bf(v0.y) << 16);
  p.y = f2bf(v0.z) | ((unsigned)f2bf(v0.w) << 16);
  p.z = f2bf(v1.x) | ((unsigned)f2bf(v1.y) << 16);
  p.w = f2bf(v1.z) | ((unsigned)f2bf(v1.w) << 16);
  *(uint4*)(a.dst[ai] + idx) = p;
}

// ---------------- K1: proj + LN + l2 stats, counted-vmcnt pipeline ----------
// Tile 16 rows x 256 cols, 4 waves (wave w owns cols w*64..+63, 4 N-frags).
// 3 LDS buffers, B staged 2 steps ahead via global_load_lds; A (fp32 f) is
// reg-staged 2 ahead (named regs) and ds_written 1 step ahead.
// Per wave per batch: 1 A-load + 4 B-gload = 5 -> steady s_waitcnt vmcnt(5).
struct ProjArgs {
  const float* f[4];
  const float* b[4];
  const float* g[4];
  const float* be[4];
  const u16* Wb[4];
  int K[4];
};

__global__ __launch_bounds__(256, 2) void proj_kernel(ProjArgs a,
                                                      u16* __restrict__ Zb,
                                                      float* __restrict__ invZ) {
  const int m = blockIdx.y;
  const int K = a.K[m];
  const int NS = K >> 5;                 // 32/32/16/8 (even, >=8)
  const float* __restrict__ F = a.f[m];
  const u16* __restrict__ Wm = a.Wb[m];

  const int tid = threadIdx.x;
  const int w = tid >> 6, l = tid & 63;
  const int rg = l >> 4, c16 = l & 15;
  const int row0 = blockIdx.x * 16;

  __shared__ u16 aS[3][512];      // [kc(4)][row(16)] chunks of 8
  __shared__ u16 bS[3][8192];     // [kc(4)][col(256)] chunks of 8
  __shared__ float pS[4][16][2];
  __shared__ float qS[4][16];
  __shared__ u16 zS[16][264];

  // A load/write maps (per-thread: float2 = 2 k-elems of one row)
  const int arow = tid >> 4;             // 0..15
  const int akk  = (tid & 15) * 2;       // 0..30
  const float* asrc = F + (size_t)(row0 + arow) * K + akk;
  const int awi = ((akk >> 3) * 16 + arow) * 8 + (akk & 7);

  f32x4 acc[4];
  #pragma unroll
  for (int i = 0; i < 4; i++) acc[i] = (f32x4){0.f, 0.f, 0.f, 0.f};

  auto bstage = [&](int nb, int k0) {
    #pragma unroll
    for (int ii = 0; ii < 4; ii++)
      gload16(Wm + (size_t)(w * 64 + l) * K + k0 + ii * 8,
              &bS[nb][(ii * 256 + w * 64) * 8]);
  };
  auto aload = [&](int t) -> float2 {
    return *(const float2*)(asrc + ((size_t)t << 5));
  };
  auto awrite = [&](int nb, float2 v) {
    unsigned p = f2bf(v.x) | ((unsigned)f2bf(v.y) << 16);
    *(unsigned*)&aS[nb][awi] = p;
  };
  auto compute = [&](int cb) {
    short8 av = *(const short8*)&aS[cb][(rg * 16 + c16) * 8];
    #pragma unroll
    for (int nf = 0; nf < 4; nf++) {
      short8 bv = *(const short8*)&bS[cb][(rg * 256 + w * 64 + nf * 16 + c16) * 8];
      acc[nf] = __builtin_amdgcn_mfma_f32_16x16x32_bf16(av, bv, acc[nf], 0, 0, 0);
    }
  };

  // prologue: batches 0 and 1 in flight; A(0) written to LDS
  float2 aA = aload(0);
  bstage(0, 0);
  float2 aB = aload(1);
  bstage(1, 32);
  awrite(0, aA);

  for (int tt = 0; tt < NS; tt += 2) {
    // ---- even step t = tt ----
    WAIT_STEADY;
    __builtin_amdgcn_s_barrier();
    if (tt + 2 < NS) { aA = aload(tt + 2); bstage((tt + 2) % 3, (tt + 2) << 5); }
    awrite((tt + 1) % 3, aB);            // tt+1 < NS always (NS even)
    compute(tt % 3);
    // ---- odd step t = tt+1 ----
    if (tt < NS - 2) WAIT_STEADY; else WAIT_LAST;
    __builtin_amdgcn_s_barrier();
    if (tt + 3 < NS) { aB = aload(tt + 3); bstage((tt + 3) % 3, (tt + 3) << 5); }
    if (tt + 2 < NS) awrite((tt + 2) % 3, aA);
    compute((tt + 1) % 3);
  }

  // ---- epilogue: bias + LayerNorm + l2 stats (4-wave col reduction) ----
  float bb[4], gg[4], ee[4];
  #pragma unroll
  for (int nf = 0; nf < 4; nf++) {
    int col = w * 64 + nf * 16 + c16;
    bb[nf] = a.b[m][col];
    gg[nf] = a.g[m][col];
    ee[nf] = a.be[m][col];
  }
  float s[4] = {0,0,0,0}, s2[4] = {0,0,0,0};
  #pragma unroll
  for (int nf = 0; nf < 4; nf++)
    #pragma unroll
    for (int j = 0; j < 4; j++) {
      float y = acc[nf][j] + bb[nf];
      acc[nf][j] = y;
      s[j] += y; s2[j] += y * y;
    }
  #pragma unroll
  for (int msk = 8; msk >= 1; msk >>= 1)
    #pragma unroll
    for (int j = 0; j < 4; j++) {
      s[j]  += __shfl_xor(s[j],  msk, 64);
      s2[j] += __shfl_xor(s2[j], msk, 64);
    }
  if (c16 == 0)
    #pragma unroll
    for (int j = 0; j < 4; j++) {
      pS[w][rg*4+j][0] = s[j];
      pS[w][rg*4+j][1] = s2[j];
    }
  __syncthreads();
  float mu[4], rs[4];
  #pragma unroll
  for (int j = 0; j < 4; j++) {
    int row = rg*4 + j;
    float st  = pS[0][row][0] + pS[1][row][0] + pS[2][row][0] + pS[3][row][0];
    float s2t = pS[0][row][1] + pS[1][row][1] + pS[2][row][1] + pS[3][row][1];
    mu[j] = st * (1.0f/256.0f);
    float var = s2t * (1.0f/256.0f) - mu[j]*mu[j];
    rs[j] = rsqrtf(var + 1e-5f);
  }
  float zs[4] = {0,0,0,0};
  #pragma unroll
  for (int nf = 0; nf < 4; nf++)
    #pragma unroll
    for (int j = 0; j < 4; j++) {
      float z = (acc[nf][j] - mu[j]) * rs[j] * gg[nf] + ee[nf];
      acc[nf][j] = z;
      zs[j] += z * z;
    }
  #pragma unroll
  for (int msk = 8; msk >= 1; msk >>= 1)
    #pragma unroll
    for (int j = 0; j < 4; j++) zs[j] += __shfl_xor(zs[j], msk, 64);
  if (c16 == 0)
    #pragma unroll
    for (int j = 0; j < 4; j++) qS[w][rg*4+j] = zs[j];
  __syncthreads();
  #pragma unroll
  for (int j = 0; j < 4; j++) {
    int row = rg*4 + j;
    float zt = qS[0][row] + qS[1][row] + qS[2][row] + qS[3][row];
    float inv = 1.0f / (sqrtf(zt) + 1e-6f);
    if (c16 == 0 && w == 0)
      invZ[(size_t)(row0 + row) * 4 + m] = inv;
  }
  #pragma unroll
  for (int nf = 0; nf < 4; nf++)
    #pragma unroll
    for (int j = 0; j < 4; j++)
      zS[rg*4 + j][w*64 + nf*16 + c16] = f2bf(acc[nf][j]);
  __syncthreads();
  #pragma unroll
  for (int i = 0; i < 2; i++) {
    int c = tid + i * 256;
    int row = c >> 5, colc = (c & 31) * 8;
    uint4 v = *(const uint4*)&zS[row][colc];
    *(uint4*)(Zb + ((size_t)(row0 + row) * 4 + m) * 256 + colc) = v;
  }
}

// ---------------- K2: dual GEMM + softmax/finalize, counted-vmcnt -----------
// Tile 64 rows x 128 cols, 4 waves (2x2): wave = 32r x 64c x {U,O}.
// BK=32, NS=8, 3 LDS buffers staged 2 ahead; 5 gloads/wave/batch -> vmcnt(5).
__global__ __launch_bounds__(256, 2) void dual_kernel(
    const u16* __restrict__ Zb,
    const u16* __restrict__ Ub,
    const u16* __restrict__ Ob,
    const float* __restrict__ invZ, const float* __restrict__ invU,
    const float* __restrict__ cls_bias, float* __restrict__ out) {
  const int tid = threadIdx.x;
  const int w = tid >> 6, l = tid & 63;
  const int wr = w >> 1, wc2 = w & 1;
  const int rg = l >> 4, c16 = l & 15;
  const int row0 = blockIdx.x * 64;
  const int col0 = blockIdx.y * 128;

  __shared__ u16 aS[3][2048];     // [kc(4)][row(64)]
  __shared__ u16 uS[3][4096];     // [kc(4)][col(128)]
  __shared__ u16 oS[3][4096];

  f32x4 accU[2][4], accO[2][4];
  #pragma unroll
  for (int i = 0; i < 2; i++)
    #pragma unroll
    for (int j = 0; j < 4; j++) {
      accU[i][j] = (f32x4){0.f, 0.f, 0.f, 0.f};
      accO[i][j] = (f32x4){0.f, 0.f, 0.f, 0.f};
    }

  auto stage = [&](int nb, int k0) {
    gload16(Zb + (size_t)(row0 + l) * 256 + k0 + w * 8, &aS[nb][w * 512]);
    #pragma unroll
    for (int jj = 0; jj < 2; jj++) {
      gload16(Ub + (size_t)(col0 + jj * 64 + l) * 256 + k0 + w * 8,
              &uS[nb][(w * 128 + jj * 64) * 8]);
      gload16(Ob + (size_t)(col0 + jj * 64 + l) * 256 + k0 + w * 8,
              &oS[nb][(w * 128 + jj * 64) * 8]);
    }
  };
  auto compute = [&](int cb) {
    short8 av0 = *(const short8*)&aS[cb][(rg * 64 + wr * 32 + c16) * 8];
    short8 av1 = *(const short8*)&aS[cb][(rg * 64 + wr * 32 + 16 + c16) * 8];
    #pragma unroll
    for (int nf = 0; nf < 4; nf++) {
      int chunk = rg * 128 + wc2 * 64 + nf * 16 + c16;
      short8 uv = *(const short8*)&uS[cb][chunk * 8];
      accU[0][nf] = __builtin_amdgcn_mfma_f32_16x16x32_bf16(av0, uv, accU[0][nf], 0, 0, 0);
      accU[1][nf] = __builtin_amdgcn_mfma_f32_16x16x32_bf16(av1, uv, accU[1][nf], 0, 0, 0);
      short8 ov = *(const short8*)&oS[cb][chunk * 8];
      accO[0][nf] = __builtin_amdgcn_mfma_f32_16x16x32_bf16(av0, ov, accO[0][nf], 0, 0, 0);
      accO[1][nf] = __builtin_amdgcn_mfma_f32_16x16x32_bf16(av1, ov, accO[1][nf], 0, 0, 0);
    }
  };

  stage(0, 0);
  stage(1, 32);
  #pragma unroll
  for (int t = 0; t < 8; t++) {
    if (t < 7) WAIT_STEADY; else WAIT_LAST;
    __builtin_amdgcn_s_barrier();
    if (t + 2 < 8) stage((t + 2) % 3, (t + 2) << 5);
    compute(t % 3);
  }

  // fused epilogue: sim, softmax over modalities (j == modality), r, contrib,
  // logits. C/D frag: row = rg*4+j (bm), col = c16.
  #pragma unroll
  for (int mf = 0; mf < 2; mf++) {
    const int bmb = row0 + wr * 32 + mf * 16 + rg * 4;
    const f32x4 iz = *(const f32x4*)&invZ[bmb];
    const int bidx = bmb >> 2;
    #pragma unroll
    for (int nf = 0; nf < 4; nf++) {
      int col = col0 + wc2 * 64 + nf * 16 + c16;
      float iu = invU[col] * INV_TAU;
      f32x4 sU = accU[mf][nf], sO = accO[mf][nf];
      float sim0 = sU[0] * iz[0] * iu;
      float sim1 = sU[1] * iz[1] * iu;
      float sim2 = sU[2] * iz[2] * iu;
      float sim3 = sU[3] * iz[3] * iu;
      float mx = fmaxf(fmaxf(sim0, sim1), fmaxf(sim2, sim3));
      float e0 = __expf(sim0 - mx), e1 = __expf(sim1 - mx);
      float e2 = __expf(sim2 - mx), e3 = __expf(sim3 - mx);
      float rinv = 1.0f / (e0 + e1 + e2 + e3);
      float r0 = e0 * rinv, r1 = e1 * rinv, r2 = e2 * rinv, r3 = e3 * rinv;
      float ct0 = sO[0] * r0, ct1 = sO[1] * r1, ct2 = sO[2] * r2, ct3 = sO[3] * r3;
      size_t sb = (size_t)bmb * Cn + col;
      out[SIM_OFF + sb]        = sim0;
      out[SIM_OFF + sb + Cn]   = sim1;
      out[SIM_OFF + sb + 2*Cn] = sim2;
      out[SIM_OFF + sb + 3*Cn] = sim3;
      out[R_OFF + sb]          = r0;
      out[R_OFF + sb + Cn]     = r1;
      out[R_OFF + sb + 2*Cn]   = r2;
      out[R_OFF + sb + 3*Cn]   = r3;
      out[CTR_OFF + sb]        = ct0;
      out[CTR_OFF + sb + Cn]   = ct1;
      out[CTR_OFF + sb + 2*Cn] = ct2;
      out[CTR_OFF + sb + 3*Cn] = ct3;
      out[LOGITS_OFF + (size_t)bidx * Cn + col] =
          ct0 + ct1 + ct2 + ct3 + cls_bias[col];
    }
  }
}

extern "C" void kernel_launch(void* const* d_in, const int* in_sizes, int n_in,
                              void* d_out, int out_size, void* d_ws, size_t ws_size,
                              hipStream_t stream) {
  const int fi[4] = {0, 5, 10, 15};
  const int Ks[4] = {1024, 1024, 512, 256};

  char* ws = (char*)d_ws;
  u16* Zb  = (u16*)(ws + 0);           // 4,194,304 B
  u16* Wb0 = (u16*)(ws + 4194304);     // 524,288
  u16* Wb1 = (u16*)(ws + 4718592);     // 524,288
  u16* Wb2 = (u16*)(ws + 5242880);     // 262,144
  u16* Wb3 = (u16*)(ws + 5505024);     // 131,072
  u16* Ub  = (u16*)(ws + 5636096);     // 262,144
  u16* Ob  = (u16*)(ws + 5898240);     // 262,144
  float* invZ = (float*)(ws + 6160384);
  float* invU = (float*)(ws + 6193152);
  u16* Wb[4] = {Wb0, Wb1, Wb2, Wb3};

  ProjArgs pa;
  for (int m = 0; m < 4; m++) {
    pa.f[m]  = (const float*)d_in[fi[m] + 0];
    pa.b[m]  = (const float*)d_in[fi[m] + 2];
    pa.g[m]  = (const float*)d_in[fi[m] + 3];
    pa.be[m] = (const float*)d_in[fi[m] + 4];
    pa.Wb[m] = Wb[m];
    pa.K[m]  = Ks[m];
  }
  const float* U        = (const float*)d_in[20];
  const float* O        = (const float*)d_in[21];
  const float* cls_bias = (const float*)d_in[22];

  CvtArgs ca;
  ca.src[0] = (const float*)d_in[1];   ca.dst[0] = Wb0;
  ca.src[1] = (const float*)d_in[6];   ca.dst[1] = Wb1;
  ca.src[2] = (const float*)d_in[11];  ca.dst[2] = Wb2;
  ca.src[3] = (const float*)d_in[16];  ca.dst[3] = Wb3;
  ca.src[4] = U;                       ca.dst[4] = Ub;
  ca.src[5] = O;                       ca.dst[5] = Ob;

  float* out = (float*)d_out;

  cvt_kernel<<<608, 256, 0, stream>>>(ca, U, invU);
  proj_kernel<<<dim3(Bn / 16, 4), 256, 0, stream>>>(pa, Zb, invZ);
  dual_kernel<<<dim3((Bn * Mn) / 64, Cn / 128), 256, 0, stream>>>(
      Zb, Ub, Ob, invZ, invU, cls_bias, out);
}

// Round 6
// 171.361 us; speedup vs baseline: 1.3304x; 1.0511x over previous
//
#include <hip/hip_runtime.h>
#include <math.h>

typedef __attribute__((ext_vector_type(8))) short short8;
typedef __attribute__((ext_vector_type(4))) float f32x4;
typedef unsigned short u16;

constexpr int Bn = 2048, Mn = 4, Cn = 512, Dn = 256;
constexpr size_t LOGITS_OFF = 0;
constexpr size_t R_OFF   = (size_t)Bn * Cn;                 // 1,048,576
constexpr size_t SIM_OFF = R_OFF + (size_t)Bn * Mn * Cn;    // 5,242,880
constexpr size_t CTR_OFF = SIM_OFF + (size_t)Bn * Mn * Cn;  // 9,437,184
constexpr float INV_TAU = 1.0f / 0.07f;

__device__ __forceinline__ unsigned short f2bf(float f) {
  unsigned u = __float_as_uint(f);
  u += 0x7fffu + ((u >> 16) & 1u);   // round-to-nearest-even
  return (unsigned short)(u >> 16);
}

__device__ __forceinline__ void gload16(const void* g, void* l) {
  __builtin_amdgcn_global_load_lds(
      (const __attribute__((address_space(1))) void*)g,
      (__attribute__((address_space(3))) void*)l, 16, 0, 0);
}

// ---------------- K0: fp32 -> bf16 (W x4, U, O) + invU ----------------------
struct CvtArgs {
  const float* src[6];
  u16* dst[6];
};

__global__ __launch_bounds__(256) void cvt_kernel(CvtArgs a,
                                                  const float* __restrict__ U,
                                                  float* __restrict__ invU) {
  const int blk = blockIdx.x;
  if (blk >= 480) {
    int c = (blk - 480) * 4 + (threadIdx.x >> 6);
    int lane = threadIdx.x & 63;
    float4 v = *(const float4*)&U[(size_t)c * Dn + lane * 4];
    float s = v.x*v.x + v.y*v.y + v.z*v.z + v.w*v.w;
    #pragma unroll
    for (int m = 32; m >= 1; m >>= 1) s += __shfl_xor(s, m, 64);
    if (lane == 0) invU[c] = 1.0f / (sqrtf(s) + 1e-6f);
    return;
  }
  int c = blk * 256 + threadIdx.x;
  const int ends[6] = {32768, 65536, 81920, 90112, 106496, 122880};
  int ai = 0, base = 0;
  #pragma unroll
  for (int i = 0; i < 5; i++)
    if (c >= ends[i]) { ai = i + 1; base = ends[i]; }
  int idx = (c - base) * 8;
  const float4* s = (const float4*)(a.src[ai] + idx);
  float4 v0 = s[0], v1 = s[1];
  uint4 p;
  p.x = f2bf(v0.x) | ((unsigned)f2bf(v0.y) << 16);
  p.y = f2bf(v0.z) | ((unsigned)f2bf(v0.w) << 16);
  p.z = f2bf(v1.x) | ((unsigned)f2bf(v1.y) << 16);
  p.w = f2bf(v1.z) | ((unsigned)f2bf(v1.w) << 16);
  *(uint4*)(a.dst[ai] + idx) = p;
}

// ---------------- K1: proj + LN + l2 stats, barrier-free K-loop -------------
// Block: 512 thr = 8 waves; tile 16 rows x 256 cols (full D -> LN in-block).
// Wave w: 16 rows x 32 cols (2 N-frags). A (f, cvt to bf16) staged in LDS ONCE
// (full K), chunk-major [kc][row] -> conflict-free ds_read_b128. B (W bf16)
// loaded per-lane directly from global each step (L2-resident). No barriers
// in the K-loop; latency hidden by unroll-4 ILP x 4 waves/SIMD.
struct ProjArgs {
  const float* f[4];
  const float* b[4];
  const float* g[4];
  const float* be[4];
  const u16* Wb[4];
  int K[4];
};

__global__ __launch_bounds__(512, 4) void proj_kernel(ProjArgs a,
                                                      u16* __restrict__ Zb,
                                                      float* __restrict__ invZ) {
  const int m = blockIdx.y;
  const int K = a.K[m];
  const int NS = K >> 5;                     // 32 / 32 / 16 / 8
  const float* __restrict__ F = a.f[m];
  const u16* __restrict__ Wm = a.Wb[m];

  const int tid = threadIdx.x;
  const int w = tid >> 6, l = tid & 63;
  const int rg = l >> 4, c16 = l & 15;
  const int row0 = blockIdx.x * 16;

  __shared__ u16 aS[16 * 1024];              // 32 KB max (16 rows x K bf16)
  __shared__ float pS[8][16][2];
  __shared__ float qS[8][16];
  __shared__ u16 zS[16][264];

  // ---- stage A once: chunk i = kc*16 + row (8 bf16 per chunk) ----
  const int niter = (K * 16) >> 12;          // K/256: 4,4,2,1
  for (int it = 0; it < niter; it++) {
    int i = it * 512 + tid;
    int row = i & 15, kc = i >> 4;
    const float* src = F + (size_t)(row0 + row) * K + kc * 8;
    float4 v0 = *(const float4*)src;
    float4 v1 = *(const float4*)(src + 4);
    short8 p;
    p[0] = (short)f2bf(v0.x); p[1] = (short)f2bf(v0.y);
    p[2] = (short)f2bf(v0.z); p[3] = (short)f2bf(v0.w);
    p[4] = (short)f2bf(v1.x); p[5] = (short)f2bf(v1.y);
    p[6] = (short)f2bf(v1.z); p[7] = (short)f2bf(v1.w);
    *(short8*)&aS[i * 8] = p;
  }
  __syncthreads();

  // ---- barrier-free K-loop ----
  f32x4 acc[2];
  acc[0] = (f32x4){0.f, 0.f, 0.f, 0.f};
  acc[1] = (f32x4){0.f, 0.f, 0.f, 0.f};
  const u16* b0p = Wm + (size_t)(w * 32 + c16) * K + rg * 8;
  const u16* b1p = b0p + (size_t)16 * K;
  const int abase = (rg * 16 + c16) * 8;     // + t*512 per step

  #pragma unroll 4
  for (int t = 0; t < NS; t++) {
    short8 av = *(const short8*)&aS[abase + t * 512];
    short8 b0 = *(const short8*)(b0p + t * 32);
    short8 b1 = *(const short8*)(b1p + t * 32);
    acc[0] = __builtin_amdgcn_mfma_f32_16x16x32_bf16(av, b0, acc[0], 0, 0, 0);
    acc[1] = __builtin_amdgcn_mfma_f32_16x16x32_bf16(av, b1, acc[1], 0, 0, 0);
  }

  // ---- epilogue: bias + LayerNorm + l2 stats (8-wave col reduction) ----
  float bb[2], gg[2], ee[2];
  #pragma unroll
  for (int nf = 0; nf < 2; nf++) {
    int col = w * 32 + nf * 16 + c16;
    bb[nf] = a.b[m][col];
    gg[nf] = a.g[m][col];
    ee[nf] = a.be[m][col];
  }
  float s[4] = {0,0,0,0}, s2[4] = {0,0,0,0};
  #pragma unroll
  for (int nf = 0; nf < 2; nf++)
    #pragma unroll
    for (int j = 0; j < 4; j++) {
      float y = acc[nf][j] + bb[nf];
      acc[nf][j] = y;
      s[j] += y; s2[j] += y * y;
    }
  #pragma unroll
  for (int msk = 8; msk >= 1; msk >>= 1)
    #pragma unroll
    for (int j = 0; j < 4; j++) {
      s[j]  += __shfl_xor(s[j],  msk, 64);
      s2[j] += __shfl_xor(s2[j], msk, 64);
    }
  if (c16 == 0)
    #pragma unroll
    for (int j = 0; j < 4; j++) {
      pS[w][rg*4+j][0] = s[j];
      pS[w][rg*4+j][1] = s2[j];
    }
  __syncthreads();
  float mu[4], rs[4];
  #pragma unroll
  for (int j = 0; j < 4; j++) {
    int row = rg*4 + j;
    float st = 0.f, s2t = 0.f;
    #pragma unroll
    for (int ww = 0; ww < 8; ww++) { st += pS[ww][row][0]; s2t += pS[ww][row][1]; }
    mu[j] = st * (1.0f/256.0f);
    float var = s2t * (1.0f/256.0f) - mu[j]*mu[j];
    rs[j] = rsqrtf(var + 1e-5f);
  }
  float zs[4] = {0,0,0,0};
  #pragma unroll
  for (int nf = 0; nf < 2; nf++)
    #pragma unroll
    for (int j = 0; j < 4; j++) {
      float z = (acc[nf][j] - mu[j]) * rs[j] * gg[nf] + ee[nf];
      acc[nf][j] = z;
      zs[j] += z * z;
    }
  #pragma unroll
  for (int msk = 8; msk >= 1; msk >>= 1)
    #pragma unroll
    for (int j = 0; j < 4; j++) zs[j] += __shfl_xor(zs[j], msk, 64);
  if (c16 == 0)
    #pragma unroll
    for (int j = 0; j < 4; j++) qS[w][rg*4+j] = zs[j];
  __syncthreads();
  #pragma unroll
  for (int j = 0; j < 4; j++) {
    int row = rg*4 + j;
    float zt = 0.f;
    #pragma unroll
    for (int ww = 0; ww < 8; ww++) zt += qS[ww][row];
    float inv = 1.0f / (sqrtf(zt) + 1e-6f);
    if (c16 == 0 && w == 0)
      invZ[(size_t)(row0 + row) * 4 + m] = inv;
  }
  #pragma unroll
  for (int nf = 0; nf < 2; nf++)
    #pragma unroll
    for (int j = 0; j < 4; j++)
      zS[rg*4 + j][w*32 + nf*16 + c16] = f2bf(acc[nf][j]);
  __syncthreads();
  {
    int row = tid >> 5, colc = (tid & 31) * 8;
    uint4 v = *(const uint4*)&zS[row][colc];
    *(uint4*)(Zb + ((size_t)(row0 + row) * 4 + m) * 256 + colc) = v;
  }
}

// ---------------- K2: dual GEMM + softmax/finalize, barrier-free ------------
// Block: 256 thr = 4 waves (2x2): wave = 32 rows x 32 cols x {U,O}
// (2 M-frags x 2 N-frags x 2 mats = 8 MFMA/step). Tile 64r x 64c.
// A (Zb) staged once via global_load_lds (linear dest); B direct from L2.
// Grid (128, 8) = 1024 blocks = 4 blocks/CU = 16 waves/CU.
__global__ __launch_bounds__(256, 4) void dual_kernel(
    const u16* __restrict__ Zb,
    const u16* __restrict__ Ub,
    const u16* __restrict__ Ob,
    const float* __restrict__ invZ, const float* __restrict__ invU,
    const float* __restrict__ cls_bias, float* __restrict__ out) {
  const int tid = threadIdx.x;
  const int w = tid >> 6, l = tid & 63;
  const int wr = w & 1, wc = w >> 1;
  const int rg = l >> 4, c16 = l & 15;
  const int row0 = blockIdx.x * 64;
  const int col0 = blockIdx.y * 64 + wc * 32;

  __shared__ u16 aS[64 * 256];               // 32 KB; chunk i = kc*64 + row

  // ---- stage A once (wave-uniform LDS base + lane*16 = linear) ----
  #pragma unroll
  for (int it = 0; it < 8; it++) {
    int i = it * 256 + tid;
    gload16(Zb + (size_t)(row0 + (i & 63)) * 256 + (i >> 6) * 8, &aS[i * 8]);
  }
  __syncthreads();

  // ---- barrier-free K-loop: 8 steps ----
  f32x4 accU[2][2], accO[2][2];              // [mf][nf]
  #pragma unroll
  for (int i = 0; i < 2; i++)
    #pragma unroll
    for (int j = 0; j < 2; j++) {
      accU[i][j] = (f32x4){0.f, 0.f, 0.f, 0.f};
      accO[i][j] = (f32x4){0.f, 0.f, 0.f, 0.f};
    }
  const u16* u0p = Ub + (size_t)(col0 + c16) * 256 + rg * 8;
  const u16* u1p = u0p + 16 * 256;
  const u16* o0p = Ob + (size_t)(col0 + c16) * 256 + rg * 8;
  const u16* o1p = o0p + 16 * 256;
  const int ab0 = (rg * 64 + wr * 32 + c16) * 8;    // + t*2048 per step
  const int ab1 = ab0 + 16 * 8;

  #pragma unroll 4
  for (int t = 0; t < 8; t++) {
    short8 a0 = *(const short8*)&aS[ab0 + t * 2048];
    short8 a1 = *(const short8*)&aS[ab1 + t * 2048];
    short8 u0 = *(const short8*)(u0p + t * 32);
    short8 u1 = *(const short8*)(u1p + t * 32);
    short8 o0 = *(const short8*)(o0p + t * 32);
    short8 o1 = *(const short8*)(o1p + t * 32);
    accU[0][0] = __builtin_amdgcn_mfma_f32_16x16x32_bf16(a0, u0, accU[0][0], 0, 0, 0);
    accU[0][1] = __builtin_amdgcn_mfma_f32_16x16x32_bf16(a0, u1, accU[0][1], 0, 0, 0);
    accU[1][0] = __builtin_amdgcn_mfma_f32_16x16x32_bf16(a1, u0, accU[1][0], 0, 0, 0);
    accU[1][1] = __builtin_amdgcn_mfma_f32_16x16x32_bf16(a1, u1, accU[1][1], 0, 0, 0);
    accO[0][0] = __builtin_amdgcn_mfma_f32_16x16x32_bf16(a0, o0, accO[0][0], 0, 0, 0);
    accO[0][1] = __builtin_amdgcn_mfma_f32_16x16x32_bf16(a0, o1, accO[0][1], 0, 0, 0);
    accO[1][0] = __builtin_amdgcn_mfma_f32_16x16x32_bf16(a1, o0, accO[1][0], 0, 0, 0);
    accO[1][1] = __builtin_amdgcn_mfma_f32_16x16x32_bf16(a1, o1, accO[1][1], 0, 0, 0);
  }

  // ---- fused epilogue: sim, softmax over modalities (j), r, contrib, logits
  #pragma unroll
  for (int mf = 0; mf < 2; mf++) {
    const int bmb = row0 + wr * 32 + mf * 16 + rg * 4;
    const f32x4 iz = *(const f32x4*)&invZ[bmb];
    const int bidx = bmb >> 2;
    #pragma unroll
    for (int nf = 0; nf < 2; nf++) {
      int col = col0 + nf * 16 + c16;
      float iu = invU[col] * INV_TAU;
      f32x4 sU = accU[mf][nf], sO = accO[mf][nf];
      float sim0 = sU[0] * iz[0] * iu;
      float sim1 = sU[1] * iz[1] * iu;
      float sim2 = sU[2] * iz[2] * iu;
      float sim3 = sU[3] * iz[3] * iu;
      float mx = fmaxf(fmaxf(sim0, sim1), fmaxf(sim2, sim3));
      float e0 = __expf(sim0 - mx), e1 = __expf(sim1 - mx);
      float e2 = __expf(sim2 - mx), e3 = __expf(sim3 - mx);
      float rinv = 1.0f / (e0 + e1 + e2 + e3);
      float r0 = e0 * rinv, r1 = e1 * rinv, r2 = e2 * rinv, r3 = e3 * rinv;
      float ct0 = sO[0] * r0, ct1 = sO[1] * r1, ct2 = sO[2] * r2, ct3 = sO[3] * r3;
      size_t sb = (size_t)bmb * Cn + col;
      out[SIM_OFF + sb]        = sim0;
      out[SIM_OFF + sb + Cn]   = sim1;
      out[SIM_OFF + sb + 2*Cn] = sim2;
      out[SIM_OFF + sb + 3*Cn] = sim3;
      out[R_OFF + sb]          = r0;
      out[R_OFF + sb + Cn]     = r1;
      out[R_OFF + sb + 2*Cn]   = r2;
      out[R_OFF + sb + 3*Cn]   = r3;
      out[CTR_OFF + sb]        = ct0;
      out[CTR_OFF + sb + Cn]   = ct1;
      out[CTR_OFF + sb + 2*Cn] = ct2;
      out[CTR_OFF + sb + 3*Cn] = ct3;
      out[LOGITS_OFF + (size_t)bidx * Cn + col] =
          ct0 + ct1 + ct2 + ct3 + cls_bias[col];
    }
  }
}

extern "C" void kernel_launch(void* const* d_in, const int* in_sizes, int n_in,
                              void* d_out, int out_size, void* d_ws, size_t ws_size,
                              hipStream_t stream) {
  const int fi[4] = {0, 5, 10, 15};
  const int Ks[4] = {1024, 1024, 512, 256};

  char* ws = (char*)d_ws;
  u16* Zb  = (u16*)(ws + 0);           // 4,194,304 B
  u16* Wb0 = (u16*)(ws + 4194304);     // 524,288
  u16* Wb1 = (u16*)(ws + 4718592);     // 524,288
  u16* Wb2 = (u16*)(ws + 5242880);     // 262,144
  u16* Wb3 = (u16*)(ws + 5505024);     // 131,072
  u16* Ub  = (u16*)(ws + 5636096);     // 262,144
  u16* Ob  = (u16*)(ws + 5898240);     // 262,144
  float* invZ = (float*)(ws + 6160384);
  float* invU = (float*)(ws + 6193152);
  u16* Wb[4] = {Wb0, Wb1, Wb2, Wb3};

  ProjArgs pa;
  for (int m = 0; m < 4; m++) {
    pa.f[m]  = (const float*)d_in[fi[m] + 0];
    pa.b[m]  = (const float*)d_in[fi[m] + 2];
    pa.g[m]  = (const float*)d_in[fi[m] + 3];
    pa.be[m] = (const float*)d_in[fi[m] + 4];
    pa.Wb[m] = Wb[m];
    pa.K[m]  = Ks[m];
  }
  const float* U        = (const float*)d_in[20];
  const float* O        = (const float*)d_in[21];
  const float* cls_bias = (const float*)d_in[22];

  CvtArgs ca;
  ca.src[0] = (const float*)d_in[1];   ca.dst[0] = Wb0;
  ca.src[1] = (const float*)d_in[6];   ca.dst[1] = Wb1;
  ca.src[2] = (const float*)d_in[11];  ca.dst[2] = Wb2;
  ca.src[3] = (const float*)d_in[16];  ca.dst[3] = Wb3;
  ca.src[4] = U;                       ca.dst[4] = Ub;
  ca.src[5] = O;                       ca.dst[5] = Ob;

  float* out = (float*)d_out;

  cvt_kernel<<<608, 256, 0, stream>>>(ca, U, invU);
  proj_kernel<<<dim3(Bn / 16, 4), 512, 0, stream>>>(pa, Zb, invZ);
  dual_kernel<<<dim3((Bn * Mn) / 64, Cn / 64), 256, 0, stream>>>(
      Zb, Ub, Ob, invZ, invU, cls_bias, out);
}

// Round 7
// 159.687 us; speedup vs baseline: 1.4276x; 1.0731x over previous
//
#include <hip/hip_runtime.h>
#include <math.h>

typedef __attribute__((ext_vector_type(8))) short short8;
typedef __attribute__((ext_vector_type(4))) float f32x4;
typedef unsigned short u16;

constexpr int Bn = 2048, Mn = 4, Cn = 512, Dn = 256;
constexpr size_t LOGITS_OFF = 0;
constexpr size_t R_OFF   = (size_t)Bn * Cn;                 // 1,048,576
constexpr size_t SIM_OFF = R_OFF + (size_t)Bn * Mn * Cn;    // 5,242,880
constexpr size_t CTR_OFF = SIM_OFF + (size_t)Bn * Mn * Cn;  // 9,437,184
constexpr float INV_TAU = 1.0f / 0.07f;

#define MFMA16(av, bv, cv) __builtin_amdgcn_mfma_f32_16x16x32_bf16(av, bv, cv, 0, 0, 0)

__device__ __forceinline__ unsigned short f2bf(float f) {
  unsigned u = __float_as_uint(f);
  u += 0x7fffu + ((u >> 16) & 1u);   // round-to-nearest-even
  return (unsigned short)(u >> 16);
}

__device__ __forceinline__ void gload16(const void* g, void* l) {
  __builtin_amdgcn_global_load_lds(
      (const __attribute__((address_space(1))) void*)g,
      (__attribute__((address_space(3))) void*)l, 16, 0, 0);
}

// ============================================================================
// Superchunk layout for a bf16 MFMA B/A operand matrix [NC rows x K]:
// frag (cg, t) covers rows cg*16..+15, k = t*32..+31. Lane l = rg*16+r16 holds
// 8 bf16 (row cg*16+r16, k t*32+rg*8..+7), stored at elem ((cg*NT+t)*64+l)*8.
// A wave's fragment fetch = ONE coalesced 1 KB load at base + l*16B.
// ============================================================================

// ---------------- K0: fp32 -> bf16 swizzled (W x4, U, O) + invU -------------
struct CvtArgs {
  const float* src[6];
  u16* dst[6];
};

__global__ __launch_bounds__(256) void cvt_kernel(CvtArgs a,
                                                  const float* __restrict__ U,
                                                  float* __restrict__ invU) {
  const int blk = blockIdx.x;
  if (blk >= 480) {
    int c = (blk - 480) * 4 + (threadIdx.x >> 6);
    int lane = threadIdx.x & 63;
    float4 v = *(const float4*)&U[(size_t)c * Dn + lane * 4];
    float s = v.x*v.x + v.y*v.y + v.z*v.z + v.w*v.w;
    #pragma unroll
    for (int m = 32; m >= 1; m >>= 1) s += __shfl_xor(s, m, 64);
    if (lane == 0) invU[c] = 1.0f / (sqrtf(s) + 1e-6f);
    return;
  }
  int c = blk * 256 + threadIdx.x;     // global chunk id, 0..122879
  const int ends[6] = {32768, 65536, 81920, 90112, 106496, 122880};
  const int Kv[6]   = {1024, 1024, 512, 256, 256, 256};
  const int lgNT[6] = {5, 5, 4, 3, 3, 3};
  int ai = 0, base = 0;
  #pragma unroll
  for (int i = 0; i < 5; i++)
    if (c >= ends[i]) { ai = i + 1; base = ends[i]; }
  const int K = Kv[ai], lg = lgNT[ai];
  int j = c - base;
  int l = j & 63;
  int tcg = j >> 6;
  int t = tcg & ((1 << lg) - 1);
  int cg = tcg >> lg;
  int col = cg * 16 + (l & 15);
  int k0 = t * 32 + (l >> 4) * 8;
  const float* s = a.src[ai] + (size_t)col * K + k0;
  float4 v0 = *(const float4*)s, v1 = *(const float4*)(s + 4);
  uint4 p;
  p.x = f2bf(v0.x) | ((unsigned)f2bf(v0.y) << 16);
  p.y = f2bf(v0.z) | ((unsigned)f2bf(v0.w) << 16);
  p.z = f2bf(v1.x) | ((unsigned)f2bf(v1.y) << 16);
  p.w = f2bf(v1.z) | ((unsigned)f2bf(v1.w) << 16);
  *(uint4*)(a.dst[ai] + (size_t)j * 8) = p;
}

// ---------------- K1: proj + LN + l2 stats ----------------------------------
// Block: 512 thr = 8 waves; tile 32 rows x 256 cols. Wave w: 32 rows x 32 cols
// (2 mf x 2 nf frags). A (f) cvt->bf16 staged in LDS once (chunk [kc][row32]);
// B (Wt, swizzled) streamed coalesced from L2. Barrier-free K-loop.
// Z written directly in superchunk layout (rows bm = b*4+m interleaved).
struct ProjArgs {
  const float* f[4];
  const float* b[4];
  const float* g[4];
  const float* be[4];
  const u16* Wt[4];
  int K[4];
};

__global__ __launch_bounds__(512, 4) void proj_kernel(ProjArgs a,
                                                      u16* __restrict__ Zb2,
                                                      float* __restrict__ invZ) {
  const int m = blockIdx.y;
  const int K = a.K[m];
  const int NT = K >> 5;                     // 32 / 32 / 16 / 8
  const float* __restrict__ F = a.f[m];
  const u16* __restrict__ Wt = a.Wt[m];

  const int tid = threadIdx.x;
  const int w = tid >> 6, l = tid & 63;
  const int rg = l >> 4, c16 = l & 15;
  const int row0 = blockIdx.x * 32;

  __shared__ __align__(16) u16 aS[32768];    // 64 KB: 32 rows x K (chunk [kc][row])
  __shared__ float pS[8][32][2];
  __shared__ float qS[8][32];

  // ---- stage A once: chunk i = kc*32 + row ----
  const int nch = K * 4;
  for (int i = tid; i < nch; i += 512) {
    int row = i & 31, kc = i >> 5;
    const float* src = F + (size_t)(row0 + row) * K + kc * 8;
    float4 v0 = *(const float4*)src, v1 = *(const float4*)(src + 4);
    short8 p;
    p[0] = (short)f2bf(v0.x); p[1] = (short)f2bf(v0.y);
    p[2] = (short)f2bf(v0.z); p[3] = (short)f2bf(v0.w);
    p[4] = (short)f2bf(v1.x); p[5] = (short)f2bf(v1.y);
    p[6] = (short)f2bf(v1.z); p[7] = (short)f2bf(v1.w);
    *(short8*)&aS[(size_t)i * 8] = p;
  }
  __syncthreads();

  // ---- barrier-free K-loop: 4 MFMA / step ----
  f32x4 acc[2][2];
  #pragma unroll
  for (int i = 0; i < 2; i++)
    #pragma unroll
    for (int j = 0; j < 2; j++) acc[i][j] = (f32x4){0.f, 0.f, 0.f, 0.f};

  const size_t bbase = ((size_t)(w * 2) * NT) * 512 + l * 8;
  const int a0b = rg * 256 + c16 * 8;        // + t*1024 (+128 for mf=1)

  #pragma unroll 4
  for (int t = 0; t < NT; t++) {
    short8 a0 = *(const short8*)&aS[a0b + t * 1024];
    short8 a1 = *(const short8*)&aS[a0b + t * 1024 + 128];
    short8 b0 = *(const short8*)(Wt + bbase + (size_t)t * 512);
    short8 b1 = *(const short8*)(Wt + bbase + (size_t)(NT + t) * 512);
    acc[0][0] = MFMA16(a0, b0, acc[0][0]);
    acc[0][1] = MFMA16(a0, b1, acc[0][1]);
    acc[1][0] = MFMA16(a1, b0, acc[1][0]);
    acc[1][1] = MFMA16(a1, b1, acc[1][1]);
  }

  // ---- epilogue: bias + LayerNorm + l2 stats (8-wave col reduction) ----
  float bb[2], gg[2], ee[2];
  #pragma unroll
  for (int nf = 0; nf < 2; nf++) {
    int col = w * 32 + nf * 16 + c16;
    bb[nf] = a.b[m][col];
    gg[nf] = a.g[m][col];
    ee[nf] = a.be[m][col];
  }
  float s[2][4] = {{0,0,0,0},{0,0,0,0}}, s2[2][4] = {{0,0,0,0},{0,0,0,0}};
  #pragma unroll
  for (int mf = 0; mf < 2; mf++)
    #pragma unroll
    for (int nf = 0; nf < 2; nf++)
      #pragma unroll
      for (int j = 0; j < 4; j++) {
        float y = acc[mf][nf][j] + bb[nf];
        acc[mf][nf][j] = y;
        s[mf][j] += y; s2[mf][j] += y * y;
      }
  #pragma unroll
  for (int msk = 8; msk >= 1; msk >>= 1)
    #pragma unroll
    for (int mf = 0; mf < 2; mf++)
      #pragma unroll
      for (int j = 0; j < 4; j++) {
        s[mf][j]  += __shfl_xor(s[mf][j],  msk, 64);
        s2[mf][j] += __shfl_xor(s2[mf][j], msk, 64);
      }
  if (c16 == 0)
    #pragma unroll
    for (int mf = 0; mf < 2; mf++)
      #pragma unroll
      for (int j = 0; j < 4; j++) {
        int row = mf * 16 + rg * 4 + j;
        pS[w][row][0] = s[mf][j];
        pS[w][row][1] = s2[mf][j];
      }
  __syncthreads();
  float mu[2][4], rs[2][4];
  #pragma unroll
  for (int mf = 0; mf < 2; mf++)
    #pragma unroll
    for (int j = 0; j < 4; j++) {
      int row = mf * 16 + rg * 4 + j;
      float st = 0.f, s2t = 0.f;
      #pragma unroll
      for (int ww = 0; ww < 8; ww++) { st += pS[ww][row][0]; s2t += pS[ww][row][1]; }
      mu[mf][j] = st * (1.0f / 256.0f);
      float var = s2t * (1.0f / 256.0f) - mu[mf][j] * mu[mf][j];
      rs[mf][j] = rsqrtf(var + 1e-5f);
    }
  float zs[2][4] = {{0,0,0,0},{0,0,0,0}};
  #pragma unroll
  for (int mf = 0; mf < 2; mf++)
    #pragma unroll
    for (int nf = 0; nf < 2; nf++)
      #pragma unroll
      for (int j = 0; j < 4; j++) {
        float z = (acc[mf][nf][j] - mu[mf][j]) * rs[mf][j] * gg[nf] + ee[nf];
        acc[mf][nf][j] = z;
        zs[mf][j] += z * z;
      }
  #pragma unroll
  for (int msk = 8; msk >= 1; msk >>= 1)
    #pragma unroll
    for (int mf = 0; mf < 2; mf++)
      #pragma unroll
      for (int j = 0; j < 4; j++) zs[mf][j] += __shfl_xor(zs[mf][j], msk, 64);
  if (c16 == 0)
    #pragma unroll
    for (int mf = 0; mf < 2; mf++)
      #pragma unroll
      for (int j = 0; j < 4; j++) qS[w][mf * 16 + rg * 4 + j] = zs[mf][j];
  __syncthreads();
  if (w == 0 && c16 == 0)
    #pragma unroll
    for (int mf = 0; mf < 2; mf++)
      #pragma unroll
      for (int j = 0; j < 4; j++) {
        int row = mf * 16 + rg * 4 + j;
        float zt = 0.f;
        #pragma unroll
        for (int ww = 0; ww < 8; ww++) zt += qS[ww][row];
        invZ[(size_t)(row0 + row) * 4 + m] = 1.0f / (sqrtf(zt) + 1e-6f);
      }

  // ---- z -> LDS transpose (alias aS; dead after barriers) -> superchunk Zb2
  u16 (*zS)[264] = (u16 (*)[264])aS;
  #pragma unroll
  for (int mf = 0; mf < 2; mf++)
    #pragma unroll
    for (int nf = 0; nf < 2; nf++)
      #pragma unroll
      for (int j = 0; j < 4; j++)
        zS[mf * 16 + rg * 4 + j][w * 32 + nf * 16 + c16] = f2bf(acc[mf][nf][j]);
  __syncthreads();
  #pragma unroll
  for (int it = 0; it < 2; it++) {
    int cI = it * 512 + tid;                 // 0..1023 chunks
    int i = cI & 3, rgs = (cI >> 2) & 3, t = (cI >> 4) & 7, gsub = cI >> 7;
    int lrow = gsub * 4 + i;
    uint4 v = *(const uint4*)&zS[lrow][t * 32 + rgs * 8];
    size_t off = ((size_t)((blockIdx.x * 8 + gsub) * 8 + t) * 64 +
                  rgs * 16 + i * 4 + m) * 8;
    *(uint4*)(Zb2 + off) = v;
  }
}

// ---------------- K2: dual GEMM + softmax/finalize --------------------------
// Block: 256 thr = 4 waves; wave w owns row-group g = bx*4+w (16 bm rows =
// 4 batch x 4 modalities -> softmax register-local) x 32 cols x {U,O}.
// B (Ut/Ot swizzled) staged once in 32 KB LDS (linear gload16); A (Zb2
// superchunks) streamed coalesced 1 KB/step. Barrier-free K-loop, 8 steps.
__global__ __launch_bounds__(256, 4) void dual_kernel(
    const u16* __restrict__ Zb2,
    const u16* __restrict__ Ut,
    const u16* __restrict__ Ot,
    const float* __restrict__ invZ, const float* __restrict__ invU,
    const float* __restrict__ cls_bias, float* __restrict__ out) {
  const int tid = threadIdx.x;
  const int w = tid >> 6, l = tid & 63;
  const int rg = l >> 4, c16 = l & 15;
  const int g = blockIdx.x * 4 + w;
  const int col0 = blockIdx.y * 32;

  __shared__ __align__(16) u16 uS[8192];     // 16 KB: 2 cg x 8 t x 64 l x 8
  __shared__ __align__(16) u16 oS[8192];

  // ---- stage B once (linear copy of swizzled region) ----
  const size_t bsrc = (size_t)blockIdx.y * 8192;
  #pragma unroll
  for (int it = 0; it < 4; it++) {
    int chunk = it * 256 + w * 64;
    gload16(Ut + bsrc + (size_t)(chunk + l) * 8, &uS[(size_t)chunk * 8]);
    gload16(Ot + bsrc + (size_t)(chunk + l) * 8, &oS[(size_t)chunk * 8]);
  }
  __syncthreads();

  // ---- barrier-free K-loop ----
  f32x4 aU[2], aO[2];
  aU[0] = (f32x4){0.f,0.f,0.f,0.f}; aU[1] = (f32x4){0.f,0.f,0.f,0.f};
  aO[0] = (f32x4){0.f,0.f,0.f,0.f}; aO[1] = (f32x4){0.f,0.f,0.f,0.f};
  const u16* ap = Zb2 + ((size_t)g * 512 + l) * 8;   // + t*512*8? no: +t*512 elems

  #pragma unroll 4
  for (int t = 0; t < 8; t++) {
    short8 av = *(const short8*)(ap + (size_t)t * 512);
    short8 u0 = *(const short8*)&uS[(size_t)t * 512 + l * 8];
    short8 u1 = *(const short8*)&uS[(size_t)(8 + t) * 512 + l * 8];
    short8 o0 = *(const short8*)&oS[(size_t)t * 512 + l * 8];
    short8 o1 = *(const short8*)&oS[(size_t)(8 + t) * 512 + l * 8];
    aU[0] = MFMA16(av, u0, aU[0]);
    aU[1] = MFMA16(av, u1, aU[1]);
    aO[0] = MFMA16(av, o0, aO[0]);
    aO[1] = MFMA16(av, o1, aO[1]);
  }

  // ---- fused epilogue: sim, softmax over modalities (j), r, contrib, logits
  const int bmb = g * 16 + rg * 4;
  const f32x4 iz = *(const f32x4*)&invZ[bmb];
  const int bidx = g * 4 + rg;
  #pragma unroll
  for (int nf = 0; nf < 2; nf++) {
    int col = col0 + nf * 16 + c16;
    float iu = invU[col] * INV_TAU;
    f32x4 sU = aU[nf], sO = aO[nf];
    float sim0 = sU[0] * iz[0] * iu;
    float sim1 = sU[1] * iz[1] * iu;
    float sim2 = sU[2] * iz[2] * iu;
    float sim3 = sU[3] * iz[3] * iu;
    float mx = fmaxf(fmaxf(sim0, sim1), fmaxf(sim2, sim3));
    float e0 = __expf(sim0 - mx), e1 = __expf(sim1 - mx);
    float e2 = __expf(sim2 - mx), e3 = __expf(sim3 - mx);
    float rinv = 1.0f / (e0 + e1 + e2 + e3);
    float r0 = e0 * rinv, r1 = e1 * rinv, r2 = e2 * rinv, r3 = e3 * rinv;
    float ct0 = sO[0] * r0, ct1 = sO[1] * r1, ct2 = sO[2] * r2, ct3 = sO[3] * r3;
    size_t sb = (size_t)bmb * Cn + col;
    out[SIM_OFF + sb]        = sim0;
    out[SIM_OFF + sb + Cn]   = sim1;
    out[SIM_OFF + sb + 2*Cn] = sim2;
    out[SIM_OFF + sb + 3*Cn] = sim3;
    out[R_OFF + sb]          = r0;
    out[R_OFF + sb + Cn]     = r1;
    out[R_OFF + sb + 2*Cn]   = r2;
    out[R_OFF + sb + 3*Cn]   = r3;
    out[CTR_OFF + sb]        = ct0;
    out[CTR_OFF + sb + Cn]   = ct1;
    out[CTR_OFF + sb + 2*Cn] = ct2;
    out[CTR_OFF + sb + 3*Cn] = ct3;
    out[LOGITS_OFF + (size_t)bidx * Cn + col] =
        ct0 + ct1 + ct2 + ct3 + cls_bias[col];
  }
}

extern "C" void kernel_launch(void* const* d_in, const int* in_sizes, int n_in,
                              void* d_out, int out_size, void* d_ws, size_t ws_size,
                              hipStream_t stream) {
  const int fi[4] = {0, 5, 10, 15};
  const int Ks[4] = {1024, 1024, 512, 256};

  char* ws = (char*)d_ws;
  u16* Zb2 = (u16*)(ws + 0);           // 4,194,304 B (superchunk layout)
  u16* Wt0 = (u16*)(ws + 4194304);     // 524,288
  u16* Wt1 = (u16*)(ws + 4718592);     // 524,288
  u16* Wt2 = (u16*)(ws + 5242880);     // 262,144
  u16* Wt3 = (u16*)(ws + 5505024);     // 131,072
  u16* Ut  = (u16*)(ws + 5636096);     // 262,144
  u16* Ot  = (u16*)(ws + 5898240);     // 262,144
  float* invZ = (float*)(ws + 6160384);
  float* invU = (float*)(ws + 6193152);
  u16* Wt[4] = {Wt0, Wt1, Wt2, Wt3};

  ProjArgs pa;
  for (int m = 0; m < 4; m++) {
    pa.f[m]  = (const float*)d_in[fi[m] + 0];
    pa.b[m]  = (const float*)d_in[fi[m] + 2];
    pa.g[m]  = (const float*)d_in[fi[m] + 3];
    pa.be[m] = (const float*)d_in[fi[m] + 4];
    pa.Wt[m] = Wt[m];
    pa.K[m]  = Ks[m];
  }
  const float* U        = (const float*)d_in[20];
  const float* O        = (const float*)d_in[21];
  const float* cls_bias = (const float*)d_in[22];

  CvtArgs ca;
  ca.src[0] = (const float*)d_in[1];   ca.dst[0] = Wt0;
  ca.src[1] = (const float*)d_in[6];   ca.dst[1] = Wt1;
  ca.src[2] = (const float*)d_in[11];  ca.dst[2] = Wt2;
  ca.src[3] = (const float*)d_in[16];  ca.dst[3] = Wt3;
  ca.src[4] = U;                       ca.dst[4] = Ut;
  ca.src[5] = O;                       ca.dst[5] = Ot;

  float* out = (float*)d_out;

  cvt_kernel<<<608, 256, 0, stream>>>(ca, U, invU);
  proj_kernel<<<dim3(Bn / 32, 4), 512, 0, stream>>>(pa, Zb2, invZ);
  dual_kernel<<<dim3((Bn * Mn) / 64, Cn / 32), 256, 0, stream>>>(
      Zb2, Ut, Ot, invZ, invU, cls_bias, out);
}